// Round 10
// baseline (1488.574 us; speedup 1.0000x reference)
//
#include <hip/hip_runtime.h>
#include <hip/hip_bf16.h>

// Problem constants (fixed by the reference)
constexpr int kN   = 50000;
constexpr int kE   = 800000;
constexpr int kIN  = 64;
constexpr int kMC  = 16;
constexpr int kH   = 4;
constexpr int kC   = 16;
constexpr int kHID = 128;
constexpr float kNEG = 0.2f;
constexpr float kEPS = 1e-5f;

__device__ __forceinline__ float lrelu(float x) { return x > 0.f ? x : kNEG * x; }

// ---------------- graph build ----------------

__global__ void k_count(const int* __restrict__ ei, int* __restrict__ cnt) {
    int e = blockIdx.x * blockDim.x + threadIdx.x;
    if (e < kE) atomicAdd(&cnt[ei[kE + e]], 1);   // dst = ei[1][e]
}

// single block, 1024 threads: exclusive scan of cnt -> rp, also dinv = rsqrt(cnt+1)
__global__ void k_scan(const int* __restrict__ cnt, int* __restrict__ rp,
                       float* __restrict__ dinv) {
    __shared__ int wsum[16];
    __shared__ int chunk_base;
    int tid = threadIdx.x, lane = tid & 63, wid = tid >> 6;
    if (tid == 0) chunk_base = 0;
    __syncthreads();
    for (int base = 0; base < kN; base += 1024) {
        int i = base + tid;
        int v = (i < kN) ? cnt[i] : 0;
        if (i < kN) dinv[i] = rsqrtf((float)(v + 1));
        // wave inclusive scan
        int s = v;
        #pragma unroll
        for (int off = 1; off < 64; off <<= 1) {
            int t = __shfl_up(s, off);
            if (lane >= off) s += t;
        }
        if (lane == 63) wsum[wid] = s;
        __syncthreads();
        if (wid == 0) {
            int t = (lane < 16) ? wsum[lane] : 0;
            #pragma unroll
            for (int off = 1; off < 16; off <<= 1) {
                int u = __shfl_up(t, off);
                if (lane >= off) t += u;
            }
            if (lane < 16) wsum[lane] = t;
        }
        __syncthreads();
        int wbase = (wid > 0) ? wsum[wid - 1] : 0;
        int total = wsum[15];
        int excl = chunk_base + wbase + s - v;
        if (i < kN) rp[i] = excl;
        __syncthreads();
        if (tid == 0) chunk_base += total;
        __syncthreads();
    }
    if (threadIdx.x == 0) rp[kN] = chunk_base;
}

__global__ void k_fill(const int* __restrict__ ei, const int* __restrict__ rp,
                       int* __restrict__ fill, int* __restrict__ col) {
    int e = blockIdx.x * blockDim.x + threadIdx.x;
    if (e < kE) {
        int d = ei[kE + e];
        int pos = rp[d] + atomicAdd(&fill[d], 1);
        col[pos] = ei[e];
    }
}

// ---------------- normalized aggregation (scalar, for F=16): ----
// out[v] = dinv[v]*(dinv[v]*in[v] + sum_u dinv[u]*in[u])

template <int F>
__global__ void k_agg(const float* __restrict__ in, float* __restrict__ out,
                      const float* __restrict__ dinv, const int* __restrict__ rp,
                      const int* __restrict__ col) {
    constexpr int NPB = 256 / F;
    int node = blockIdx.x * NPB + threadIdx.x / F;
    int f = threadIdx.x % F;
    if (node >= kN) return;
    float dv = dinv[node];
    float acc = dv * in[(size_t)node * F + f];     // self loop term (dinv[v]^2 * in[v]) /dv
    int b = rp[node], e2 = rp[node + 1];
    for (int i = b; i < e2; ++i) {
        int u = col[i];
        acc += dinv[u] * in[(size_t)u * F + f];
    }
    out[(size_t)node * F + f] = dv * acc;
}

// ---- aggregation for F=128 over PRE-SCALED input (Ps = dinv .* mf):
// out[v] = dinv[v] * (Ps[v] + sum_u Ps[u]). Chunked coalesced col loads + shfl broadcast.

__global__ void k_agg128v(const float* __restrict__ in, float* __restrict__ out,
                          const float* __restrict__ dinv, const int* __restrict__ rp,
                          const int* __restrict__ col) {
    int node = blockIdx.x * 8 + threadIdx.x / 32;   // 8 nodes per 256-thread block
    int l = threadIdx.x & 31;                       // float4 col index
    if (node >= kN) return;
    const float4* in4 = (const float4*)in;
    float dv = dinv[node];
    float4 acc = in4[(size_t)node * 32 + l];        // self term Ps[v]
    int b = rp[node], e2 = rp[node + 1];
    for (int base = b; base < e2; base += 32) {
        int idx = base + l;
        int myu = (idx < e2) ? col[idx] : 0;        // coalesced chunk of indices
        int n = min(32, e2 - base);
        for (int cc = 0; cc < n; ++cc) {
            int u = __shfl(myu, cc, 32);            // uniform broadcast (register)
            float4 w = in4[(size_t)u * 32 + l];     // independent row load
            acc.x += w.x; acc.y += w.y; acc.z += w.z; acc.w += w.w;
        }
    }
    ((float4*)out)[(size_t)node * 32 + l] =
        make_float4(dv * acc.x, dv * acc.y, dv * acc.z, dv * acc.w);
}

// ---------------- Ps = dinv .* relu(am @ w0 + b0), am: N x 16, w0: 16 x 128 ----------------

__global__ void k_mf(const float* __restrict__ am, const float* __restrict__ w0,
                     const float* __restrict__ b0, const float* __restrict__ dinv,
                     float* __restrict__ mf) {
    __shared__ float w[16 * 128];
    __shared__ float a[16 * 16];
    int tid = threadIdx.x;
    int n0 = blockIdx.x * 16;
    {   // stage w0: 2048 floats = 512 float4, 2 per thread
        const float4* w04 = (const float4*)w0;
        float4* w4 = (float4*)w;
        #pragma unroll
        for (int i = 0; i < 2; ++i) w4[tid + 256 * i] = w04[tid + 256 * i];
        // stage am tile: 256 floats = 64 float4
        if (tid < 64) {
            const float4* am4 = (const float4*)am;   // row = 4 float4
            int node = n0 + tid / 4;
            ((float4*)a)[tid] = (node < kN) ? am4[(size_t)node * 4 + (tid & 3)]
                                            : make_float4(0.f, 0.f, 0.f, 0.f);
        }
    }
    __syncthreads();
    int f = tid % 128, g = tid / 128;   // g in {0,1}
    float bf = b0[f];
    for (int j = 0; j < 8; ++j) {
        int nl = g * 8 + j;
        int node = n0 + nl;
        if (node < kN) {
            float acc = bf;
            #pragma unroll
            for (int k = 0; k < 16; ++k) acc += a[nl * 16 + k] * w[k * 128 + f];
            mf[(size_t)node * 128 + f] = dinv[node] * fmaxf(acc, 0.f);
        }
    }
}

// ---------------- BatchNorm stats (biased var) over N rows of 64 cols ----------------

__global__ void k_bnstats(const float* __restrict__ x, float* __restrict__ stats) {
    int f = threadIdx.x % 64, r0 = threadIdx.x / 64;  // 4 row groups
    float s = 0.f, s2 = 0.f;
    for (int v = blockIdx.x * 4 + r0; v < kN; v += gridDim.x * 4) {
        float val = x[(size_t)v * 64 + f];
        s += val; s2 += val * val;
    }
    __shared__ float sh[256], sh2[256];
    sh[threadIdx.x] = s; sh2[threadIdx.x] = s2;
    __syncthreads();
    if (threadIdx.x < 64) {
        s  = sh[threadIdx.x]  + sh[threadIdx.x + 64]  + sh[threadIdx.x + 128]  + sh[threadIdx.x + 192];
        s2 = sh2[threadIdx.x] + sh2[threadIdx.x + 64] + sh2[threadIdx.x + 128] + sh2[threadIdx.x + 192];
        atomicAdd(&stats[f], s);
        atomicAdd(&stats[64 + f], s2);
    }
}

__global__ void k_bnfin(const float* __restrict__ stats, float* __restrict__ mu_rstd) {
    int f = threadIdx.x;
    if (f < 64) {
        float mu = stats[f] / (float)kN;
        float var = stats[64 + f] / (float)kN - mu * mu;
        mu_rstd[f] = mu;
        mu_rstd[64 + f] = rsqrtf(var + kEPS);
    }
}

// ---------------- FUSED SPADE + GAT-input: ----------------
// phase 1: y = leaky(BN(x)*(1+amf@wg+bg) + amf@wb+bb)   (y kept in regs/LDS only)
// phase 2: h = y @ W ; es/ed per (node, head)
// LDS phase-aliased in one 24 KB block -> 6 blocks/CU.

__global__ void k_spgat(const float* __restrict__ xin, const float* __restrict__ amf,
                        const float* __restrict__ wg, const float* __restrict__ bg,
                        const float* __restrict__ wb, const float* __restrict__ bb,
                        const float* __restrict__ mu_rstd,
                        const float* __restrict__ W, const float* __restrict__ as_,
                        const float* __restrict__ ad_,
                        float* __restrict__ h, float* __restrict__ esed) {
    __shared__ float smem[6144];   // 24 KB
    float* a   = smem;             // phase 1: [16][128] amf tile (8 KB)
    float* wgs = smem + 2048;      // phase 1: [32][64] gamma chunk (8 KB)
    float* wbs = smem + 4096;      // phase 1: [32][64] beta chunk (8 KB)
    float* ys  = smem;             // phase 2: [16][64] y tile (4 KB, aliases a)
    float* ws  = smem + 1024;      // phase 2: [64][64] W (16 KB, aliases a-tail/wgs/wbs)
    int tid = threadIdx.x;
    int n0 = blockIdx.x * 16;
    {   // stage amf tile via float4
        const float4* amf4 = (const float4*)amf;    // row = 32 float4
        float4* a4 = (float4*)a;
        #pragma unroll
        for (int i = 0; i < 2; ++i) {
            int idx = tid + 256 * i;
            int node = n0 + idx / 32;
            a4[idx] = (node < kN) ? amf4[(size_t)node * 32 + (idx & 31)]
                                  : make_float4(0.f, 0.f, 0.f, 0.f);
        }
    }
    int f = tid % 64, nl = tid / 64;
    float accg[4] = {0, 0, 0, 0}, accb[4] = {0, 0, 0, 0};
    const float4* wg4 = (const float4*)wg;   // [128][64] = 2048 float4; chunk = 512
    const float4* wb4 = (const float4*)wb;
    for (int c = 0; c < 4; ++c) {
        __syncthreads();   // c=0: a-tile visible; c>0: previous chunk fully consumed
        {
            float4* wgs4 = (float4*)wgs;
            float4* wbs4 = (float4*)wbs;
            #pragma unroll
            for (int i = 0; i < 2; ++i) {
                int idx = tid + 256 * i;
                wgs4[idx] = wg4[c * 512 + idx];
                wbs4[idx] = wb4[c * 512 + idx];
            }
        }
        __syncthreads();
        #pragma unroll
        for (int kk = 0; kk < 32; ++kk) {
            float wgk = wgs[kk * 64 + f], wbk = wbs[kk * 64 + f];
            int k = c * 32 + kk;
            #pragma unroll
            for (int j = 0; j < 4; ++j) {
                float av = a[(j * 4 + nl) * 128 + k];
                accg[j] += av * wgk;
                accb[j] += av * wbk;
            }
        }
    }
    float mu = mu_rstd[f], rstd = mu_rstd[64 + f];
    float bgf = bg[f], bbf = bb[f];
    float yv[4];
    #pragma unroll
    for (int j = 0; j < 4; ++j) {
        int node = n0 + j * 4 + nl;
        if (node < kN) {
            float xv = xin[(size_t)node * 64 + f];
            float g = accg[j] + bgf, b = accb[j] + bbf;
            yv[j] = lrelu((xv - mu) * rstd * (1.f + g) + b);
        } else yv[j] = 0.f;
    }
    __syncthreads();   // done reading a/wgs/wbs -> safe to overwrite
    #pragma unroll
    for (int j = 0; j < 4; ++j) ys[(j * 4 + nl) * 64 + f] = yv[j];
    {   // stage W: 4096 floats = 1024 float4, 4 per thread
        const float4* W4 = (const float4*)W;
        float4* ws4 = (float4*)ws;
        #pragma unroll
        for (int i = 0; i < 4; ++i) ws4[tid + 256 * i] = W4[tid + 256 * i];
    }
    __syncthreads();
    float asf = as_[f], adf = ad_[f];
    float acc[4] = {0, 0, 0, 0};
    for (int k = 0; k < 64; ++k) {
        float w = ws[k * 64 + f];                    // LDS consecutive (free)
        #pragma unroll
        for (int j = 0; j < 4; ++j) acc[j] += ys[(j * 4 + nl) * 64 + k] * w;  // broadcast
    }
    #pragma unroll
    for (int j = 0; j < 4; ++j) {
        int node = n0 + j * 4 + nl;
        float hv = acc[j];
        float es = hv * asf, ed = hv * adf;
        #pragma unroll
        for (int off = 1; off < 16; off <<= 1) {
            es += __shfl_xor(es, off);
            ed += __shfl_xor(ed, off);
        }
        if (node < kN) {
            h[(size_t)node * 64 + f] = hv;
            if ((f & 15) == 0) {
                int hh = f >> 4;
                esed[node * 8 + hh] = es;
                esed[node * 8 + 4 + hh] = ed;
            }
        }
    }
}

// ---------------- GAT aggregate: ONLINE softmax, chunked col loads ----------------

__global__ void k_gatagg(const float* __restrict__ h, const float* __restrict__ esed,
                         const int* __restrict__ rp, const int* __restrict__ col,
                         const float* __restrict__ bias, float* __restrict__ out) {
    int node = blockIdx.x * 4 + threadIdx.x / 64;
    if (node >= kN) return;
    int lane = threadIdx.x & 63;
    int hh = lane >> 4;
    float edv = esed[node * 8 + 4 + hh];
    float m = lrelu(esed[node * 8 + hh] + edv);   // self edge (p = 1 at current max)
    float d = 1.f;
    float acc = h[(size_t)node * 64 + lane];
    int b = rp[node], e2 = rp[node + 1];
    for (int base = b; base < e2; base += 64) {
        int idx = base + lane;
        int myu = (idx < e2) ? col[idx] : 0;       // coalesced chunk of indices
        int n = min(64, e2 - base);
        for (int cc = 0; cc < n; ++cc) {
            int u = __shfl(myu, cc);               // register broadcast
            float e = lrelu(esed[u * 8 + hh] + edv);
            float hu = h[(size_t)u * 64 + lane];   // independent coalesced row
            if (e <= m) {
                float p = __expf(e - m);
                d += p;
                acc += p * hu;
            } else {
                float s = __expf(m - e);
                d = d * s + 1.f;
                acc = acc * s + hu;
                m = e;
            }
        }
    }
    out[(size_t)node * 64 + lane] = acc / d + bias[lane];
}

// ---------------- final add ----------------

__global__ void k_add(const float4* __restrict__ a, const float4* __restrict__ b,
                      float4* __restrict__ o, int n4) {
    int i = blockIdx.x * blockDim.x + threadIdx.x;
    if (i < n4) {
        float4 x = a[i], y = b[i];
        o[i] = make_float4(x.x + y.x, x.y + y.y, x.z + y.z, x.w + y.w);
    }
}

// ---------------- host ----------------

extern "C" void kernel_launch(void* const* d_in, const int* in_sizes, int n_in,
                              void* d_out, int out_size, void* d_ws, size_t ws_size,
                              hipStream_t stream) {
    const float* x    = (const float*)d_in[0];
    const float* mask = (const float*)d_in[1];
    const int*   ei   = (const int*)d_in[2];
    const float* s_w0[3] = {(const float*)d_in[3],  (const float*)d_in[9],  (const float*)d_in[15]};
    const float* s_b0[3] = {(const float*)d_in[4],  (const float*)d_in[10], (const float*)d_in[16]};
    const float* s_wg[3] = {(const float*)d_in[5],  (const float*)d_in[11], (const float*)d_in[17]};
    const float* s_bg[3] = {(const float*)d_in[6],  (const float*)d_in[12], (const float*)d_in[18]};
    const float* s_wb[3] = {(const float*)d_in[7],  (const float*)d_in[13], (const float*)d_in[19]};
    const float* s_bb[3] = {(const float*)d_in[8],  (const float*)d_in[14], (const float*)d_in[20]};
    const float* g_w[3]  = {(const float*)d_in[21], (const float*)d_in[25], (const float*)d_in[29]};
    const float* g_b[3]  = {(const float*)d_in[22], (const float*)d_in[26], (const float*)d_in[30]};
    const float* g_as[3] = {(const float*)d_in[23], (const float*)d_in[27], (const float*)d_in[31]};
    const float* g_ad[3] = {(const float*)d_in[24], (const float*)d_in[28], (const float*)d_in[32]};

    // workspace layout
    char* base = (char*)d_ws;
    size_t off = 0;
    auto alloc = [&](size_t bytes) -> void* {
        void* p = base + off;
        off = (off + bytes + 255) & ~(size_t)255;
        return p;
    };
    int*   cnt   = (int*)alloc((size_t)kN * 4);
    int*   rp    = (int*)alloc((size_t)(kN + 1) * 4);
    int*   fill  = (int*)alloc((size_t)kN * 4);
    int*   col   = (int*)alloc((size_t)kE * 4);
    float* dinv  = (float*)alloc((size_t)kN * 4);
    float* am    = (float*)alloc((size_t)kN * 16 * 4);
    float* P     = (float*)alloc((size_t)kN * 128 * 4);   // Ps (dinv-scaled mf)
    float* Q     = (float*)alloc((size_t)kN * 128 * 4);   // amf
    float* tH    = (float*)alloc((size_t)kN * 64 * 4);    // gat h
    float* tZ    = (float*)alloc((size_t)kN * 64 * 4);    // z1 -> later zk
    float* tZ2   = (float*)alloc((size_t)kN * 64 * 4);    // z2
    float* esed  = (float*)alloc((size_t)kN * 8 * 4);
    float* sraw  = (float*)alloc(128 * 4);
    float* st_x  = (float*)alloc(128 * 4);                // mu/rstd of x
    float* st_z  = (float*)alloc(128 * 4);                // mu/rstd of z1
    (void)ws_size; (void)n_in; (void)in_sizes; (void)out_size;

    const int EB = (kE + 255) / 256;

    // graph build
    hipMemsetAsync(cnt, 0, (size_t)kN * 4, stream);
    hipMemsetAsync(fill, 0, (size_t)kN * 4, stream);
    k_count<<<EB, 256, 0, stream>>>(ei, cnt);
    k_scan<<<1, 1024, 0, stream>>>(cnt, rp, dinv);
    k_fill<<<EB, 256, 0, stream>>>(ei, rp, fill, col);

    // shared: am = A(mask), BN stats of x
    k_agg<16><<<(kN + 15) / 16, 256, 0, stream>>>(mask, am, dinv, rp, col);
    hipMemsetAsync(sraw, 0, 128 * 4, stream);
    k_bnstats<<<256, 256, 0, stream>>>(x, sraw);
    k_bnfin<<<1, 64, 0, stream>>>(sraw, st_x);

    const int GB16 = (kN + 15) / 16;   // 3125
    const int GB8  = (kN + 7) / 8;     // 6250 (k_agg128v)
    const int GB4  = (kN + 3) / 4;     // 12500

    // ---- s1 + g1 ----
    k_mf<<<GB16, 256, 0, stream>>>(am, s_w0[0], s_b0[0], dinv, P);
    k_agg128v<<<GB8, 256, 0, stream>>>(P, Q, dinv, rp, col);
    k_spgat<<<GB16, 256, 0, stream>>>(x, Q, s_wg[0], s_bg[0], s_wb[0], s_bb[0], st_x,
                                      g_w[0], g_as[0], g_ad[0], tH, esed);
    k_gatagg<<<GB4, 256, 0, stream>>>(tH, esed, rp, col, g_b[0], tZ);

    // ---- s2 + g2 (BN over z1) ----
    hipMemsetAsync(sraw, 0, 128 * 4, stream);
    k_bnstats<<<256, 256, 0, stream>>>(tZ, sraw);
    k_bnfin<<<1, 64, 0, stream>>>(sraw, st_z);
    k_mf<<<GB16, 256, 0, stream>>>(am, s_w0[1], s_b0[1], dinv, P);
    k_agg128v<<<GB8, 256, 0, stream>>>(P, Q, dinv, rp, col);
    k_spgat<<<GB16, 256, 0, stream>>>(tZ, Q, s_wg[1], s_bg[1], s_wb[1], s_bb[1], st_z,
                                      g_w[1], g_as[1], g_ad[1], tH, esed);
    k_gatagg<<<GB4, 256, 0, stream>>>(tH, esed, rp, col, g_b[1], tZ2);

    // ---- sk + gk (BN over x, shared stats) ----
    k_mf<<<GB16, 256, 0, stream>>>(am, s_w0[2], s_b0[2], dinv, P);
    k_agg128v<<<GB8, 256, 0, stream>>>(P, Q, dinv, rp, col);
    k_spgat<<<GB16, 256, 0, stream>>>(x, Q, s_wg[2], s_bg[2], s_wb[2], s_bb[2], st_x,
                                      g_w[2], g_as[2], g_ad[2], tH, esed);
    k_gatagg<<<GB4, 256, 0, stream>>>(tH, esed, rp, col, g_b[2], tZ);  // z1 dead, reuse

    // out = z2 + zk
    k_add<<<(kN * 64 / 4 + 255) / 256, 256, 0, stream>>>((const float4*)tZ2, (const float4*)tZ,
                                                         (float4*)d_out, kN * 64 / 4);
}

// Round 11
// 1240.154 us; speedup vs baseline: 1.2003x; 1.2003x over previous
//
#include <hip/hip_runtime.h>
#include <hip/hip_fp16.h>

// Problem constants (fixed by the reference)
constexpr int kN   = 50000;
constexpr int kE   = 800000;
constexpr float kNEG = 0.2f;
constexpr float kEPS = 1e-5f;
constexpr int kNB16 = kN / 16;   // 3125 blocks of 16 nodes (exact)

__device__ __forceinline__ float lrelu(float x) { return x > 0.f ? x : kNEG * x; }

__device__ __forceinline__ void unpack8(int4 raw, float* t) {
    __half2* h = (__half2*)&raw;
    #pragma unroll
    for (int i = 0; i < 4; ++i) { float2 f = __half22float2(h[i]); t[2*i] = f.x; t[2*i+1] = f.y; }
}

// ---------------- graph build ----------------

__global__ void k_count(const int* __restrict__ ei, int* __restrict__ cnt) {
    int e = blockIdx.x * blockDim.x + threadIdx.x;
    if (e < kE) atomicAdd(&cnt[ei[kE + e]], 1);   // dst = ei[1][e]
}

__global__ void k_scan(const int* __restrict__ cnt, int* __restrict__ rp,
                       float* __restrict__ dinv) {
    __shared__ int wsum[16];
    __shared__ int chunk_base;
    int tid = threadIdx.x, lane = tid & 63, wid = tid >> 6;
    if (tid == 0) chunk_base = 0;
    __syncthreads();
    for (int base = 0; base < kN; base += 1024) {
        int i = base + tid;
        int v = (i < kN) ? cnt[i] : 0;
        if (i < kN) dinv[i] = rsqrtf((float)(v + 1));
        int s = v;
        #pragma unroll
        for (int off = 1; off < 64; off <<= 1) {
            int t = __shfl_up(s, off);
            if (lane >= off) s += t;
        }
        if (lane == 63) wsum[wid] = s;
        __syncthreads();
        if (wid == 0) {
            int t = (lane < 16) ? wsum[lane] : 0;
            #pragma unroll
            for (int off = 1; off < 16; off <<= 1) {
                int u = __shfl_up(t, off);
                if (lane >= off) t += u;
            }
            if (lane < 16) wsum[lane] = t;
        }
        __syncthreads();
        int wbase = (wid > 0) ? wsum[wid - 1] : 0;
        int total = wsum[15];
        int excl = chunk_base + wbase + s - v;
        if (i < kN) rp[i] = excl;
        __syncthreads();
        if (tid == 0) chunk_base += total;
        __syncthreads();
    }
    if (threadIdx.x == 0) rp[kN] = chunk_base;
}

__global__ void k_fill(const int* __restrict__ ei, const int* __restrict__ rp,
                       int* __restrict__ fill, int* __restrict__ col) {
    int e = blockIdx.x * blockDim.x + threadIdx.x;
    if (e < kE) {
        int d = ei[kE + e];
        int pos = rp[d] + atomicAdd(&fill[d], 1);
        col[pos] = ei[e];
    }
}

// ---------------- combo: {agg16(mask)->am} || {bnstats(x)->sraw_x} ----------------

__global__ void k_combo(const float* __restrict__ mask, const float* __restrict__ x,
                        const float* __restrict__ dinv, const int* __restrict__ rp,
                        const int* __restrict__ col,
                        float* __restrict__ am, float* __restrict__ sraw_x) {
    if (blockIdx.x < kNB16) {
        int node = blockIdx.x * 16 + threadIdx.x / 16;
        int f = threadIdx.x % 16;
        float dv = dinv[node];
        float acc = dv * mask[(size_t)node * 16 + f];
        int b = rp[node], e2 = rp[node + 1];
        for (int i = b; i < e2; ++i) {
            int u = col[i];
            acc += dinv[u] * mask[(size_t)u * 16 + f];
        }
        am[(size_t)node * 16 + f] = dv * acc;
    } else {
        int bb = blockIdx.x - kNB16;   // 0..255
        int f = threadIdx.x % 64, r0 = threadIdx.x / 64;
        float s = 0.f, s2 = 0.f;
        for (int v = bb * 4 + r0; v < kN; v += 256 * 4) {
            float val = x[(size_t)v * 64 + f];
            s += val; s2 += val * val;
        }
        __shared__ float sh[256], sh2[256];
        sh[threadIdx.x] = s; sh2[threadIdx.x] = s2;
        __syncthreads();
        if (threadIdx.x < 64) {
            s  = sh[threadIdx.x]  + sh[threadIdx.x + 64]  + sh[threadIdx.x + 128]  + sh[threadIdx.x + 192];
            s2 = sh2[threadIdx.x] + sh2[threadIdx.x + 64] + sh2[threadIdx.x + 128] + sh2[threadIdx.x + 192];
            atomicAdd(&sraw_x[f], s);
            atomicAdd(&sraw_x[64 + f], s2);
        }
    }
}

// ---------------- BN stats over z1 ----------------

__global__ void k_bnstats(const float* __restrict__ x, float* __restrict__ stats) {
    int f = threadIdx.x % 64, r0 = threadIdx.x / 64;
    float s = 0.f, s2 = 0.f;
    for (int v = blockIdx.x * 4 + r0; v < kN; v += gridDim.x * 4) {
        float val = x[(size_t)v * 64 + f];
        s += val; s2 += val * val;
    }
    __shared__ float sh[256], sh2[256];
    sh[threadIdx.x] = s; sh2[threadIdx.x] = s2;
    __syncthreads();
    if (threadIdx.x < 64) {
        s  = sh[threadIdx.x]  + sh[threadIdx.x + 64]  + sh[threadIdx.x + 128]  + sh[threadIdx.x + 192];
        s2 = sh2[threadIdx.x] + sh2[threadIdx.x + 64] + sh2[threadIdx.x + 128] + sh2[threadIdx.x + 192];
        atomicAdd(&stats[f], s);
        atomicAdd(&stats[64 + f], s2);
    }
}

// ---------------- Ps = dinv .* relu(am @ w0 + b0)  (fp16 out; optionally 2 sets) ----------------

__global__ void k_mf2(const float* __restrict__ am,
                      const float* __restrict__ w0a, const float* __restrict__ b0a,
                      const float* __restrict__ w0b, const float* __restrict__ b0b,
                      const float* __restrict__ dinv,
                      __half* __restrict__ Pa, __half* __restrict__ Pb) {
    int set = blockIdx.x / kNB16;            // 0 or 1
    int blk = blockIdx.x - set * kNB16;
    const float* w0 = set ? w0b : w0a;
    const float* b0 = set ? b0b : b0a;
    __half* P = set ? Pb : Pa;
    __shared__ float w[16 * 128];
    __shared__ float a[16 * 16];
    int tid = threadIdx.x;
    int n0 = blk * 16;
    {
        const float4* w04 = (const float4*)w0;
        float4* w4 = (float4*)w;
        #pragma unroll
        for (int i = 0; i < 2; ++i) w4[tid + 256 * i] = w04[tid + 256 * i];
        if (tid < 64) {
            const float4* am4 = (const float4*)am;
            int node = n0 + tid / 4;
            ((float4*)a)[tid] = am4[(size_t)node * 4 + (tid & 3)];
        }
    }
    __syncthreads();
    int f = tid % 128, g = tid / 128;
    float bf = b0[f];
    for (int j = 0; j < 8; ++j) {
        int nl = g * 8 + j;
        int node = n0 + nl;
        float acc = bf;
        #pragma unroll
        for (int k = 0; k < 16; ++k) acc += a[nl * 16 + k] * w[k * 128 + f];
        P[(size_t)node * 128 + f] = __float2half(dinv[node] * fmaxf(acc, 0.f));
    }
}

// ---------------- Q = dinv .* (P[v] + sum_u P[u])  (fp16 rows, f32 accum; 2 sets) ----------------
// 16 lanes/node x int4 (8 halves); chunked coalesced col loads + shfl broadcast.

__global__ void k_aggh(const __half* __restrict__ Pa, const __half* __restrict__ Pb,
                       __half* __restrict__ Qa, __half* __restrict__ Qb,
                       const float* __restrict__ dinv, const int* __restrict__ rp,
                       const int* __restrict__ col) {
    int set = blockIdx.x / kNB16;
    int blk = blockIdx.x - set * kNB16;
    const int4* in = (const int4*)(set ? Pb : Pa);
    int4* out = (int4*)(set ? Qb : Qa);
    int node = blk * 16 + threadIdx.x / 16;
    int l = threadIdx.x & 15;                 // int4 index within 256-B row
    float dv = dinv[node];
    float acc[8];
    unpack8(in[(size_t)node * 16 + l], acc);  // self term
    int b = rp[node], e2 = rp[node + 1];
    for (int base = b; base < e2; base += 16) {
        int idx = base + l;
        int myu = (idx < e2) ? col[idx] : 0;
        int n = min(16, e2 - base);
        for (int cc = 0; cc < n; ++cc) {
            int u = __shfl(myu, cc, 16);
            float t[8];
            unpack8(in[(size_t)u * 16 + l], t);
            #pragma unroll
            for (int q = 0; q < 8; ++q) acc[q] += t[q];
        }
    }
    int4 r;
    __half2* hp = (__half2*)&r;
    #pragma unroll
    for (int i = 0; i < 4; ++i) hp[i] = __floats2half2_rn(dv * acc[2*i], dv * acc[2*i+1]);
    out[(size_t)node * 16 + l] = r;
}

// ---------------- FUSED SPADE + GAT-input (A/B block split for batching) ----------------

struct SpgatArgs {
    const float* xin; const __half* Q;
    const float *wg, *bg, *wb, *bb, *sraw, *W, *as_, *ad_;
    __half* h; float* esed; int eslot;
};

__global__ void k_spgat(SpgatArgs A, SpgatArgs B) {
    SpgatArgs P = (blockIdx.x < kNB16) ? A : B;
    int blk = (blockIdx.x < kNB16) ? blockIdx.x : blockIdx.x - kNB16;
    __shared__ float smem[6144];   // 24 KB, phase-aliased
    float* a   = smem;             // phase 1: [16][128] amf tile
    float* wgs = smem + 2048;      // phase 1: gamma chunk [32][64]
    float* wbs = smem + 4096;      // phase 1: beta chunk
    float* ys  = smem;             // phase 2: [16][64] y tile
    float* ws  = smem + 1024;      // phase 2: [64][64] W
    int tid = threadIdx.x;
    int n0 = blk * 16;
    {   // stage Q tile (fp16 -> f32 LDS): 256 int4s, 1 per thread
        const int4* q4 = (const int4*)P.Q;    // row = 16 int4
        int node = n0 + tid / 16, h8 = tid & 15;
        float t[8];
        unpack8(q4[(size_t)node * 16 + h8], t);
        float* dst = a + (tid / 16) * 128 + h8 * 8;
        ((float4*)dst)[0] = make_float4(t[0], t[1], t[2], t[3]);
        ((float4*)dst)[1] = make_float4(t[4], t[5], t[6], t[7]);
    }
    int f = tid % 64, nl = tid / 64;
    float accg[4] = {0,0,0,0}, accb[4] = {0,0,0,0};
    const float4* wg4 = (const float4*)P.wg;
    const float4* wb4 = (const float4*)P.wb;
    for (int c = 0; c < 4; ++c) {
        __syncthreads();
        {
            float4* wgs4 = (float4*)wgs;
            float4* wbs4 = (float4*)wbs;
            #pragma unroll
            for (int i = 0; i < 2; ++i) {
                int idx = tid + 256 * i;
                wgs4[idx] = wg4[c * 512 + idx];
                wbs4[idx] = wb4[c * 512 + idx];
            }
        }
        __syncthreads();
        #pragma unroll
        for (int kk = 0; kk < 32; ++kk) {
            float wgk = wgs[kk * 64 + f], wbk = wbs[kk * 64 + f];
            int k = c * 32 + kk;
            #pragma unroll
            for (int j = 0; j < 4; ++j) {
                float av = a[(j * 4 + nl) * 128 + k];
                accg[j] += av * wgk;
                accb[j] += av * wbk;
            }
        }
    }
    // inline BN finalize from raw sums
    float mu, rstd;
    {
        float s = P.sraw[f], s2 = P.sraw[64 + f];
        mu = s * (1.f / kN);
        rstd = rsqrtf(s2 * (1.f / kN) - mu * mu + kEPS);
    }
    float bgf = P.bg[f], bbf = P.bb[f];
    float yv[4];
    #pragma unroll
    for (int j = 0; j < 4; ++j) {
        int node = n0 + j * 4 + nl;
        float xv = P.xin[(size_t)node * 64 + f];
        float g = accg[j] + bgf, b = accb[j] + bbf;
        yv[j] = lrelu((xv - mu) * rstd * (1.f + g) + b);
    }
    __syncthreads();   // done with a/wgs/wbs
    #pragma unroll
    for (int j = 0; j < 4; ++j) ys[(j * 4 + nl) * 64 + f] = yv[j];
    {
        const float4* W4 = (const float4*)P.W;
        float4* ws4 = (float4*)ws;
        #pragma unroll
        for (int i = 0; i < 4; ++i) ws4[tid + 256 * i] = W4[tid + 256 * i];
    }
    __syncthreads();
    float asf = P.as_[f], adf = P.ad_[f];
    float acc[4] = {0,0,0,0};
    for (int k = 0; k < 64; ++k) {
        float w = ws[k * 64 + f];
        #pragma unroll
        for (int j = 0; j < 4; ++j) acc[j] += ys[(j * 4 + nl) * 64 + k] * w;
    }
    #pragma unroll
    for (int j = 0; j < 4; ++j) {
        int node = n0 + j * 4 + nl;
        float hv = acc[j];
        float es = hv * asf, ed = hv * adf;
        #pragma unroll
        for (int off = 1; off < 16; off <<= 1) {
            es += __shfl_xor(es, off);
            ed += __shfl_xor(ed, off);
        }
        P.h[(size_t)node * 64 + f] = __float2half(hv);
        if ((f & 15) == 0) {
            int hh = f >> 4;
            P.esed[node * 16 + P.eslot + hh] = es;
            P.esed[node * 16 + P.eslot + 4 + hh] = ed;
        }
    }
}

// ---------------- GAT aggregate (single, g1): online softmax -> z1 (f32) ----------------

__global__ void k_gatagg1(const __half* __restrict__ h, const float* __restrict__ esed,
                          const int* __restrict__ rp, const int* __restrict__ col,
                          const float* __restrict__ bias, float* __restrict__ out) {
    int node = blockIdx.x * 4 + threadIdx.x / 64;
    int lane = threadIdx.x & 63;
    int hh = lane >> 4;
    float edv = esed[node * 16 + 4 + hh];
    float m = lrelu(esed[node * 16 + hh] + edv);
    float d = 1.f;
    float acc = __half2float(h[(size_t)node * 64 + lane]);
    int b = rp[node], e2 = rp[node + 1];
    for (int base = b; base < e2; base += 64) {
        int idx = base + lane;
        int myu = (idx < e2) ? col[idx] : 0;
        int n = min(64, e2 - base);
        for (int cc = 0; cc < n; ++cc) {
            int u = __shfl(myu, cc);
            float e = lrelu(esed[u * 16 + hh] + edv);
            float hu = __half2float(h[(size_t)u * 64 + lane]);
            if (e <= m) {
                float p = __expf(e - m);
                d += p; acc += p * hu;
            } else {
                float s = __expf(m - e);
                d = d * s + 1.f; acc = acc * s + hu; m = e;
            }
        }
    }
    out[(size_t)node * 64 + lane] = acc / d + bias[lane];
}

// ---------------- FUSED GAT aggregate for g2 + gk + final add -> d_out ----------------

__global__ void k_gatagg2(const __half* __restrict__ h2, const __half* __restrict__ hk,
                          const float* __restrict__ esed,
                          const int* __restrict__ rp, const int* __restrict__ col,
                          const float* __restrict__ b2, const float* __restrict__ bk,
                          float* __restrict__ out) {
    int node = blockIdx.x * 4 + threadIdx.x / 64;
    int lane = threadIdx.x & 63;
    int hh = lane >> 4;
    float ed2 = esed[node * 16 + 4 + hh];
    float edk = esed[node * 16 + 12 + hh];
    float m2 = lrelu(esed[node * 16 + hh] + ed2);
    float mk = lrelu(esed[node * 16 + 8 + hh] + edk);
    float d2 = 1.f, dk = 1.f;
    float a2 = __half2float(h2[(size_t)node * 64 + lane]);
    float ak = __half2float(hk[(size_t)node * 64 + lane]);
    int b = rp[node], e2 = rp[node + 1];
    for (int base = b; base < e2; base += 64) {
        int idx = base + lane;
        int myu = (idx < e2) ? col[idx] : 0;
        int n = min(64, e2 - base);
        for (int cc = 0; cc < n; ++cc) {
            int u = __shfl(myu, cc);
            float q2 = lrelu(esed[u * 16 + hh] + ed2);
            float qk = lrelu(esed[u * 16 + 8 + hh] + edk);
            float h2u = __half2float(h2[(size_t)u * 64 + lane]);
            float hku = __half2float(hk[(size_t)u * 64 + lane]);
            if (q2 <= m2) { float p = __expf(q2 - m2); d2 += p; a2 += p * h2u; }
            else { float s = __expf(m2 - q2); d2 = d2 * s + 1.f; a2 = a2 * s + h2u; m2 = q2; }
            if (qk <= mk) { float p = __expf(qk - mk); dk += p; ak += p * hku; }
            else { float s = __expf(mk - qk); dk = dk * s + 1.f; ak = ak * s + hku; mk = qk; }
        }
    }
    out[(size_t)node * 64 + lane] = a2 / d2 + b2[lane] + ak / dk + bk[lane];
}

// ---------------- host ----------------

extern "C" void kernel_launch(void* const* d_in, const int* in_sizes, int n_in,
                              void* d_out, int out_size, void* d_ws, size_t ws_size,
                              hipStream_t stream) {
    const float* x    = (const float*)d_in[0];
    const float* mask = (const float*)d_in[1];
    const int*   ei   = (const int*)d_in[2];
    const float* s_w0[3] = {(const float*)d_in[3],  (const float*)d_in[9],  (const float*)d_in[15]};
    const float* s_b0[3] = {(const float*)d_in[4],  (const float*)d_in[10], (const float*)d_in[16]};
    const float* s_wg[3] = {(const float*)d_in[5],  (const float*)d_in[11], (const float*)d_in[17]};
    const float* s_bg[3] = {(const float*)d_in[6],  (const float*)d_in[12], (const float*)d_in[18]};
    const float* s_wb[3] = {(const float*)d_in[7],  (const float*)d_in[13], (const float*)d_in[19]};
    const float* s_bb[3] = {(const float*)d_in[8],  (const float*)d_in[14], (const float*)d_in[20]};
    const float* g_w[3]  = {(const float*)d_in[21], (const float*)d_in[25], (const float*)d_in[29]};
    const float* g_b[3]  = {(const float*)d_in[22], (const float*)d_in[26], (const float*)d_in[30]};
    const float* g_as[3] = {(const float*)d_in[23], (const float*)d_in[27], (const float*)d_in[31]};
    const float* g_ad[3] = {(const float*)d_in[24], (const float*)d_in[28], (const float*)d_in[32]};

    char* base = (char*)d_ws;
    size_t off = 0;
    auto alloc = [&](size_t bytes) -> void* {
        void* p = base + off;
        off = (off + bytes + 255) & ~(size_t)255;
        return p;
    };
    // zero-init region (ONE memset): cnt, fill, sraw_x, sraw_z — contiguous
    int*   cnt    = (int*)alloc((size_t)kN * 4);
    int*   fill   = (int*)alloc((size_t)kN * 4);
    float* sraw_x = (float*)alloc(128 * 4);
    float* sraw_z = (float*)alloc(128 * 4);
    size_t zero_span = off;
    int*    rp    = (int*)alloc((size_t)(kN + 1) * 4);
    int*    col   = (int*)alloc((size_t)kE * 4);
    float*  dinv  = (float*)alloc((size_t)kN * 4);
    float*  am    = (float*)alloc((size_t)kN * 16 * 4);
    __half* Pa    = (__half*)alloc((size_t)kN * 128 * 2);
    __half* Pb    = (__half*)alloc((size_t)kN * 128 * 2);
    __half* Qa    = (__half*)alloc((size_t)kN * 128 * 2);
    __half* Qb    = (__half*)alloc((size_t)kN * 128 * 2);
    __half* hA    = (__half*)alloc((size_t)kN * 64 * 2);
    __half* hB    = (__half*)alloc((size_t)kN * 64 * 2);
    float*  esed  = (float*)alloc((size_t)kN * 16 * 4);
    float*  z1    = (float*)alloc((size_t)kN * 64 * 4);
    (void)ws_size; (void)n_in; (void)in_sizes; (void)out_size;

    const int EB = (kE + 255) / 256;
    const int GB4 = kN / 4;   // 12500

    // 1: merged zero-init
    hipMemsetAsync(cnt, 0, zero_span, stream);
    // 2-4: graph build
    k_count<<<EB, 256, 0, stream>>>(ei, cnt);
    k_scan<<<1, 1024, 0, stream>>>(cnt, rp, dinv);
    k_fill<<<EB, 256, 0, stream>>>(ei, rp, fill, col);
    // 5: am = A(mask) || bnstats(x)
    k_combo<<<kNB16 + 256, 256, 0, stream>>>(mask, x, dinv, rp, col, am, sraw_x);

    // ---- stage 1: s1 + g1 ----
    k_mf2<<<kNB16, 256, 0, stream>>>(am, s_w0[0], s_b0[0], s_w0[0], s_b0[0], dinv, Pa, Pb);
    k_aggh<<<kNB16, 256, 0, stream>>>(Pa, Pb, Qa, Qb, dinv, rp, col);
    {
        SpgatArgs A{x, Qa, s_wg[0], s_bg[0], s_wb[0], s_bb[0], sraw_x,
                    g_w[0], g_as[0], g_ad[0], hA, esed, 0};
        k_spgat<<<kNB16, 256, 0, stream>>>(A, A);
    }
    k_gatagg1<<<GB4, 256, 0, stream>>>(hA, esed, rp, col, g_b[0], z1);

    // ---- stage 2: BN(z1); batched (s2 | sk) + fused (g2 | gk | add) ----
    k_bnstats<<<256, 256, 0, stream>>>(z1, sraw_z);
    k_mf2<<<2 * kNB16, 256, 0, stream>>>(am, s_w0[1], s_b0[1], s_w0[2], s_b0[2], dinv, Pa, Pb);
    k_aggh<<<2 * kNB16, 256, 0, stream>>>(Pa, Pb, Qa, Qb, dinv, rp, col);
    {
        SpgatArgs A{z1, Qa, s_wg[1], s_bg[1], s_wb[1], s_bb[1], sraw_z,
                    g_w[1], g_as[1], g_ad[1], hA, esed, 0};
        SpgatArgs B{x,  Qb, s_wg[2], s_bg[2], s_wb[2], s_bb[2], sraw_x,
                    g_w[2], g_as[2], g_ad[2], hB, esed, 8};
        k_spgat<<<2 * kNB16, 256, 0, stream>>>(A, B);
    }
    k_gatagg2<<<GB4, 256, 0, stream>>>(hA, hB, esed, rp, col, g_b[1], g_b[2], (float*)d_out);
}

// Round 12
// 1203.616 us; speedup vs baseline: 1.2368x; 1.0304x over previous
//
#include <hip/hip_runtime.h>
#include <hip/hip_fp16.h>

// Problem constants (fixed by the reference)
constexpr int kN   = 50000;
constexpr int kE   = 800000;
constexpr float kNEG = 0.2f;
constexpr float kEPS = 1e-5f;
constexpr int kNB16 = kN / 16;   // 3125 blocks of 16 nodes (exact)

__device__ __forceinline__ float lrelu(float x) { return x > 0.f ? x : kNEG * x; }

__device__ __forceinline__ void unpack8(int4 raw, float* t) {
    __half2* h = (__half2*)&raw;
    #pragma unroll
    for (int i = 0; i < 4; ++i) { float2 f = __half22float2(h[i]); t[2*i] = f.x; t[2*i+1] = f.y; }
}

// ---------------- graph build ----------------

__global__ void k_count(const int* __restrict__ ei, int* __restrict__ cnt) {
    int e = blockIdx.x * blockDim.x + threadIdx.x;
    if (e < kE) atomicAdd(&cnt[ei[kE + e]], 1);   // dst = ei[1][e]
}

__global__ void k_scan(const int* __restrict__ cnt, int* __restrict__ rp,
                       float* __restrict__ dinv) {
    __shared__ int wsum[16];
    __shared__ int chunk_base;
    int tid = threadIdx.x, lane = tid & 63, wid = tid >> 6;
    if (tid == 0) chunk_base = 0;
    __syncthreads();
    for (int base = 0; base < kN; base += 1024) {
        int i = base + tid;
        int v = (i < kN) ? cnt[i] : 0;
        if (i < kN) dinv[i] = rsqrtf((float)(v + 1));
        int s = v;
        #pragma unroll
        for (int off = 1; off < 64; off <<= 1) {
            int t = __shfl_up(s, off);
            if (lane >= off) s += t;
        }
        if (lane == 63) wsum[wid] = s;
        __syncthreads();
        if (wid == 0) {
            int t = (lane < 16) ? wsum[lane] : 0;
            #pragma unroll
            for (int off = 1; off < 16; off <<= 1) {
                int u = __shfl_up(t, off);
                if (lane >= off) t += u;
            }
            if (lane < 16) wsum[lane] = t;
        }
        __syncthreads();
        int wbase = (wid > 0) ? wsum[wid - 1] : 0;
        int total = wsum[15];
        int excl = chunk_base + wbase + s - v;
        if (i < kN) rp[i] = excl;
        __syncthreads();
        if (tid == 0) chunk_base += total;
        __syncthreads();
    }
    if (threadIdx.x == 0) rp[kN] = chunk_base;
}

__global__ void k_fill(const int* __restrict__ ei, const int* __restrict__ rp,
                       int* __restrict__ fill, int* __restrict__ col) {
    int e = blockIdx.x * blockDim.x + threadIdx.x;
    if (e < kE) {
        int d = ei[kE + e];
        int pos = rp[d] + atomicAdd(&fill[d], 1);
        col[pos] = ei[e];
    }
}

// ---------------- combo: {agg16(mask)->am} || {bnstats(x)->sraw_x} ----------------

__global__ void k_combo(const float* __restrict__ mask, const float* __restrict__ x,
                        const float* __restrict__ dinv, const int* __restrict__ rp,
                        const int* __restrict__ col,
                        float* __restrict__ am, float* __restrict__ sraw_x) {
    if (blockIdx.x < kNB16) {
        int node = blockIdx.x * 16 + threadIdx.x / 16;
        int f = threadIdx.x % 16;
        float dv = dinv[node];
        float acc = dv * mask[(size_t)node * 16 + f];
        int b = rp[node], e2 = rp[node + 1];
        for (int i = b; i < e2; ++i) {
            int u = col[i];
            acc += dinv[u] * mask[(size_t)u * 16 + f];
        }
        am[(size_t)node * 16 + f] = dv * acc;
    } else {
        int bb = blockIdx.x - kNB16;   // 0..255
        int f = threadIdx.x % 64, r0 = threadIdx.x / 64;
        float s = 0.f, s2 = 0.f;
        for (int v = bb * 4 + r0; v < kN; v += 256 * 4) {
            float val = x[(size_t)v * 64 + f];
            s += val; s2 += val * val;
        }
        __shared__ float sh[256], sh2[256];
        sh[threadIdx.x] = s; sh2[threadIdx.x] = s2;
        __syncthreads();
        if (threadIdx.x < 64) {
            s  = sh[threadIdx.x]  + sh[threadIdx.x + 64]  + sh[threadIdx.x + 128]  + sh[threadIdx.x + 192];
            s2 = sh2[threadIdx.x] + sh2[threadIdx.x + 64] + sh2[threadIdx.x + 128] + sh2[threadIdx.x + 192];
            atomicAdd(&sraw_x[f], s);
            atomicAdd(&sraw_x[64 + f], s2);
        }
    }
}

// ---------------- BN stats over z1 ----------------

__global__ void k_bnstats(const float* __restrict__ x, float* __restrict__ stats) {
    int f = threadIdx.x % 64, r0 = threadIdx.x / 64;
    float s = 0.f, s2 = 0.f;
    for (int v = blockIdx.x * 4 + r0; v < kN; v += gridDim.x * 4) {
        float val = x[(size_t)v * 64 + f];
        s += val; s2 += val * val;
    }
    __shared__ float sh[256], sh2[256];
    sh[threadIdx.x] = s; sh2[threadIdx.x] = s2;
    __syncthreads();
    if (threadIdx.x < 64) {
        s  = sh[threadIdx.x]  + sh[threadIdx.x + 64]  + sh[threadIdx.x + 128]  + sh[threadIdx.x + 192];
        s2 = sh2[threadIdx.x] + sh2[threadIdx.x + 64] + sh2[threadIdx.x + 128] + sh2[threadIdx.x + 192];
        atomicAdd(&stats[f], s);
        atomicAdd(&stats[64 + f], s2);
    }
}

// ---------------- Ps = dinv .* relu(am @ w0 + b0)  (fp16 out; optionally 2 sets) ----------------

__global__ void k_mf2(const float* __restrict__ am,
                      const float* __restrict__ w0a, const float* __restrict__ b0a,
                      const float* __restrict__ w0b, const float* __restrict__ b0b,
                      const float* __restrict__ dinv,
                      __half* __restrict__ Pa, __half* __restrict__ Pb) {
    int set = blockIdx.x / kNB16;            // 0 or 1
    int blk = blockIdx.x - set * kNB16;
    const float* w0 = set ? w0b : w0a;
    const float* b0 = set ? b0b : b0a;
    __half* P = set ? Pb : Pa;
    __shared__ float w[16 * 128];
    __shared__ float a[16 * 16];
    int tid = threadIdx.x;
    int n0 = blk * 16;
    {
        const float4* w04 = (const float4*)w0;
        float4* w4 = (float4*)w;
        #pragma unroll
        for (int i = 0; i < 2; ++i) w4[tid + 256 * i] = w04[tid + 256 * i];
        if (tid < 64) {
            const float4* am4 = (const float4*)am;
            int node = n0 + tid / 4;
            ((float4*)a)[tid] = am4[(size_t)node * 4 + (tid & 3)];
        }
    }
    __syncthreads();
    int f = tid % 128, g = tid / 128;
    float bf = b0[f];
    for (int j = 0; j < 8; ++j) {
        int nl = g * 8 + j;
        int node = n0 + nl;
        float acc = bf;
        #pragma unroll
        for (int k = 0; k < 16; ++k) acc += a[nl * 16 + k] * w[k * 128 + f];
        P[(size_t)node * 128 + f] = __float2half(dinv[node] * fmaxf(acc, 0.f));
    }
}

// ---------------- FUSED CSR-gather(Q) + SPADE + GAT-input ----------------
// phase 0: Q tile = dinv .* (P[v] + sum_u P[u])   (gathered straight into LDS)
// phase 1: y = leaky(BN(x)*(1+Q@wg+bg) + Q@wb+bb)
// phase 2: h = y @ W ; es/ed per (node, head)

struct SpgatArgs {
    const float* xin; const __half* P;
    const float *wg, *bg, *wb, *bb, *sraw, *W, *as_, *ad_;
    __half* h; float* esed; int eslot;
};

__global__ void k_spgat(SpgatArgs A, SpgatArgs B,
                        const float* __restrict__ dinv, const int* __restrict__ rp,
                        const int* __restrict__ col) {
    SpgatArgs G = (blockIdx.x < kNB16) ? A : B;
    int blk = (blockIdx.x < kNB16) ? blockIdx.x : blockIdx.x - kNB16;
    __shared__ float smem[6144];   // 24 KB, phase-aliased
    float* a   = smem;             // phase 0/1: [16][128] Q tile
    float* wgs = smem + 2048;      // phase 1: gamma chunk [32][64]
    float* wbs = smem + 4096;      // phase 1: beta chunk
    float* ys  = smem;             // phase 2: [16][64] y tile
    float* ws  = smem + 1024;      // phase 2: [64][64] W
    int tid = threadIdx.x;
    int n0 = blk * 16;
    {   // phase 0: CSR gather of P rows -> Q tile in LDS (16 lanes/node, f32 accum)
        int node = n0 + tid / 16;
        int l = tid & 15;                       // int4 index within 256-B fp16 row
        const int4* P4 = (const int4*)G.P;
        float dv = dinv[node];
        float acc[8];
        unpack8(P4[(size_t)node * 16 + l], acc);   // self term
        int b = rp[node], e2 = rp[node + 1];
        for (int base = b; base < e2; base += 16) {
            int idx = base + l;
            int myu = (idx < e2) ? col[idx] : 0;   // coalesced chunk of indices
            int n = min(16, e2 - base);
            for (int cc = 0; cc < n; ++cc) {
                int u = __shfl(myu, cc, 16);
                float t[8];
                unpack8(P4[(size_t)u * 16 + l], t);
                #pragma unroll
                for (int q = 0; q < 8; ++q) acc[q] += t[q];
            }
        }
        float* dst = a + (tid / 16) * 128 + l * 8;
        ((float4*)dst)[0] = make_float4(dv * acc[0], dv * acc[1], dv * acc[2], dv * acc[3]);
        ((float4*)dst)[1] = make_float4(dv * acc[4], dv * acc[5], dv * acc[6], dv * acc[7]);
    }
    int f = tid % 64, nl = tid / 64;
    float accg[4] = {0,0,0,0}, accb[4] = {0,0,0,0};
    const float4* wg4 = (const float4*)G.wg;
    const float4* wb4 = (const float4*)G.wb;
    for (int c = 0; c < 4; ++c) {
        __syncthreads();   // c=0: Q tile visible; c>0: previous chunk consumed
        {
            float4* wgs4 = (float4*)wgs;
            float4* wbs4 = (float4*)wbs;
            #pragma unroll
            for (int i = 0; i < 2; ++i) {
                int idx = tid + 256 * i;
                wgs4[idx] = wg4[c * 512 + idx];
                wbs4[idx] = wb4[c * 512 + idx];
            }
        }
        __syncthreads();
        #pragma unroll
        for (int kk = 0; kk < 32; ++kk) {
            float wgk = wgs[kk * 64 + f], wbk = wbs[kk * 64 + f];
            int k = c * 32 + kk;
            #pragma unroll
            for (int j = 0; j < 4; ++j) {
                float av = a[(j * 4 + nl) * 128 + k];
                accg[j] += av * wgk;
                accb[j] += av * wbk;
            }
        }
    }
    // inline BN finalize from raw sums
    float mu, rstd;
    {
        float s = G.sraw[f], s2 = G.sraw[64 + f];
        mu = s * (1.f / kN);
        rstd = rsqrtf(s2 * (1.f / kN) - mu * mu + kEPS);
    }
    float bgf = G.bg[f], bbf = G.bb[f];
    float yv[4];
    #pragma unroll
    for (int j = 0; j < 4; ++j) {
        int node = n0 + j * 4 + nl;
        float xv = G.xin[(size_t)node * 64 + f];
        float g = accg[j] + bgf, b = accb[j] + bbf;
        yv[j] = lrelu((xv - mu) * rstd * (1.f + g) + b);
    }
    __syncthreads();   // done with a/wgs/wbs
    #pragma unroll
    for (int j = 0; j < 4; ++j) ys[(j * 4 + nl) * 64 + f] = yv[j];
    {
        const float4* W4 = (const float4*)G.W;
        float4* ws4 = (float4*)ws;
        #pragma unroll
        for (int i = 0; i < 4; ++i) ws4[tid + 256 * i] = W4[tid + 256 * i];
    }
    __syncthreads();
    float asf = G.as_[f], adf = G.ad_[f];
    float acc[4] = {0,0,0,0};
    for (int k = 0; k < 64; ++k) {
        float w = ws[k * 64 + f];
        #pragma unroll
        for (int j = 0; j < 4; ++j) acc[j] += ys[(j * 4 + nl) * 64 + k] * w;
    }
    #pragma unroll
    for (int j = 0; j < 4; ++j) {
        int node = n0 + j * 4 + nl;
        float hv = acc[j];
        float es = hv * asf, ed = hv * adf;
        #pragma unroll
        for (int off = 1; off < 16; off <<= 1) {
            es += __shfl_xor(es, off);
            ed += __shfl_xor(ed, off);
        }
        G.h[(size_t)node * 64 + f] = __float2half(hv);
        if ((f & 15) == 0) {
            int hh = f >> 4;
            G.esed[node * 16 + G.eslot + hh] = es;
            G.esed[node * 16 + G.eslot + 4 + hh] = ed;
        }
    }
}

// ---------------- GAT aggregate (single, g1): online softmax -> z1 (f32) ----------------

__global__ void k_gatagg1(const __half* __restrict__ h, const float* __restrict__ esed,
                          const int* __restrict__ rp, const int* __restrict__ col,
                          const float* __restrict__ bias, float* __restrict__ out) {
    int node = blockIdx.x * 4 + threadIdx.x / 64;
    int lane = threadIdx.x & 63;
    int hh = lane >> 4;
    float edv = esed[node * 16 + 4 + hh];
    float m = lrelu(esed[node * 16 + hh] + edv);
    float d = 1.f;
    float acc = __half2float(h[(size_t)node * 64 + lane]);
    int b = rp[node], e2 = rp[node + 1];
    for (int base = b; base < e2; base += 64) {
        int idx = base + lane;
        int myu = (idx < e2) ? col[idx] : 0;
        int n = min(64, e2 - base);
        for (int cc = 0; cc < n; ++cc) {
            int u = __shfl(myu, cc);
            float e = lrelu(esed[u * 16 + hh] + edv);
            float hu = __half2float(h[(size_t)u * 64 + lane]);
            if (e <= m) {
                float p = __expf(e - m);
                d += p; acc += p * hu;
            } else {
                float s = __expf(m - e);
                d = d * s + 1.f; acc = acc * s + hu; m = e;
            }
        }
    }
    out[(size_t)node * 64 + lane] = acc / d + bias[lane];
}

// ---------------- FUSED GAT aggregate for g2 + gk + final add -> d_out ----------------

__global__ void k_gatagg2(const __half* __restrict__ h2, const __half* __restrict__ hk,
                          const float* __restrict__ esed,
                          const int* __restrict__ rp, const int* __restrict__ col,
                          const float* __restrict__ b2, const float* __restrict__ bk,
                          float* __restrict__ out) {
    int node = blockIdx.x * 4 + threadIdx.x / 64;
    int lane = threadIdx.x & 63;
    int hh = lane >> 4;
    float ed2 = esed[node * 16 + 4 + hh];
    float edk = esed[node * 16 + 12 + hh];
    float m2 = lrelu(esed[node * 16 + hh] + ed2);
    float mk = lrelu(esed[node * 16 + 8 + hh] + edk);
    float d2 = 1.f, dk = 1.f;
    float a2 = __half2float(h2[(size_t)node * 64 + lane]);
    float ak = __half2float(hk[(size_t)node * 64 + lane]);
    int b = rp[node], e2 = rp[node + 1];
    for (int base = b; base < e2; base += 64) {
        int idx = base + lane;
        int myu = (idx < e2) ? col[idx] : 0;
        int n = min(64, e2 - base);
        for (int cc = 0; cc < n; ++cc) {
            int u = __shfl(myu, cc);
            float q2 = lrelu(esed[u * 16 + hh] + ed2);
            float qk = lrelu(esed[u * 16 + 8 + hh] + edk);
            float h2u = __half2float(h2[(size_t)u * 64 + lane]);
            float hku = __half2float(hk[(size_t)u * 64 + lane]);
            if (q2 <= m2) { float p = __expf(q2 - m2); d2 += p; a2 += p * h2u; }
            else { float s = __expf(m2 - q2); d2 = d2 * s + 1.f; a2 = a2 * s + h2u; m2 = q2; }
            if (qk <= mk) { float p = __expf(qk - mk); dk += p; ak += p * hku; }
            else { float s = __expf(mk - qk); dk = dk * s + 1.f; ak = ak * s + hku; mk = qk; }
        }
    }
    out[(size_t)node * 64 + lane] = a2 / d2 + b2[lane] + ak / dk + bk[lane];
}

// ---------------- host ----------------

extern "C" void kernel_launch(void* const* d_in, const int* in_sizes, int n_in,
                              void* d_out, int out_size, void* d_ws, size_t ws_size,
                              hipStream_t stream) {
    const float* x    = (const float*)d_in[0];
    const float* mask = (const float*)d_in[1];
    const int*   ei   = (const int*)d_in[2];
    const float* s_w0[3] = {(const float*)d_in[3],  (const float*)d_in[9],  (const float*)d_in[15]};
    const float* s_b0[3] = {(const float*)d_in[4],  (const float*)d_in[10], (const float*)d_in[16]};
    const float* s_wg[3] = {(const float*)d_in[5],  (const float*)d_in[11], (const float*)d_in[17]};
    const float* s_bg[3] = {(const float*)d_in[6],  (const float*)d_in[12], (const float*)d_in[18]};
    const float* s_wb[3] = {(const float*)d_in[7],  (const float*)d_in[13], (const float*)d_in[19]};
    const float* s_bb[3] = {(const float*)d_in[8],  (const float*)d_in[14], (const float*)d_in[20]};
    const float* g_w[3]  = {(const float*)d_in[21], (const float*)d_in[25], (const float*)d_in[29]};
    const float* g_b[3]  = {(const float*)d_in[22], (const float*)d_in[26], (const float*)d_in[30]};
    const float* g_as[3] = {(const float*)d_in[23], (const float*)d_in[27], (const float*)d_in[31]};
    const float* g_ad[3] = {(const float*)d_in[24], (const float*)d_in[28], (const float*)d_in[32]};

    char* base = (char*)d_ws;
    size_t off = 0;
    auto alloc = [&](size_t bytes) -> void* {
        void* p = base + off;
        off = (off + bytes + 255) & ~(size_t)255;
        return p;
    };
    // zero-init region (ONE memset): cnt, fill, sraw_x, sraw_z — contiguous
    int*   cnt    = (int*)alloc((size_t)kN * 4);
    int*   fill   = (int*)alloc((size_t)kN * 4);
    float* sraw_x = (float*)alloc(128 * 4);
    float* sraw_z = (float*)alloc(128 * 4);
    size_t zero_span = off;
    int*    rp    = (int*)alloc((size_t)(kN + 1) * 4);
    int*    col   = (int*)alloc((size_t)kE * 4);
    float*  dinv  = (float*)alloc((size_t)kN * 4);
    float*  am    = (float*)alloc((size_t)kN * 16 * 4);
    __half* Pa    = (__half*)alloc((size_t)kN * 128 * 2);
    __half* Pb    = (__half*)alloc((size_t)kN * 128 * 2);
    __half* hA    = (__half*)alloc((size_t)kN * 64 * 2);
    __half* hB    = (__half*)alloc((size_t)kN * 64 * 2);
    float*  esed  = (float*)alloc((size_t)kN * 16 * 4);
    float*  z1    = (float*)alloc((size_t)kN * 64 * 4);
    (void)ws_size; (void)n_in; (void)in_sizes; (void)out_size;

    const int EB = (kE + 255) / 256;
    const int GB4 = kN / 4;   // 12500

    // 1: merged zero-init
    hipMemsetAsync(cnt, 0, zero_span, stream);
    // 2-4: graph build
    k_count<<<EB, 256, 0, stream>>>(ei, cnt);
    k_scan<<<1, 1024, 0, stream>>>(cnt, rp, dinv);
    k_fill<<<EB, 256, 0, stream>>>(ei, rp, fill, col);
    // 5: am = A(mask) || bnstats(x)
    k_combo<<<kNB16 + 256, 256, 0, stream>>>(mask, x, dinv, rp, col, am, sraw_x);

    // ---- stage 1: s1 + g1 ----
    k_mf2<<<kNB16, 256, 0, stream>>>(am, s_w0[0], s_b0[0], s_w0[0], s_b0[0], dinv, Pa, Pb);
    {
        SpgatArgs A{x, Pa, s_wg[0], s_bg[0], s_wb[0], s_bb[0], sraw_x,
                    g_w[0], g_as[0], g_ad[0], hA, esed, 0};
        k_spgat<<<kNB16, 256, 0, stream>>>(A, A, dinv, rp, col);
    }
    k_gatagg1<<<GB4, 256, 0, stream>>>(hA, esed, rp, col, g_b[0], z1);

    // ---- stage 2: BN(z1); batched (s2 | sk) + fused (g2 | gk | add) ----
    k_bnstats<<<256, 256, 0, stream>>>(z1, sraw_z);
    k_mf2<<<2 * kNB16, 256, 0, stream>>>(am, s_w0[1], s_b0[1], s_w0[2], s_b0[2], dinv, Pa, Pb);
    {
        SpgatArgs A{z1, Pa, s_wg[1], s_bg[1], s_wb[1], s_bb[1], sraw_z,
                    g_w[1], g_as[1], g_ad[1], hA, esed, 0};
        SpgatArgs B{x,  Pb, s_wg[2], s_bg[2], s_wb[2], s_bb[2], sraw_x,
                    g_w[2], g_as[2], g_ad[2], hB, esed, 8};
        k_spgat<<<2 * kNB16, 256, 0, stream>>>(A, B, dinv, rp, col);
    }
    k_gatagg2<<<GB4, 256, 0, stream>>>(hA, hB, esed, rp, col, g_b[1], g_b[2], (float*)d_out);
}